// Round 7
// baseline (180.212 us; speedup 1.0000x reference)
//
#include <hip/hip_runtime.h>
#include <hip/hip_bf16.h>

#define BB 2
#define TT 2048
#define CC 1024
#define NHEAD 16
#define DHEAD 64
#define MM (BB*TT)
#define KVB 64

using bf16 = __hip_bfloat16;
typedef __bf16 bf16x8 __attribute__((ext_vector_type(8)));
typedef __bf16 bf16x4 __attribute__((ext_vector_type(4)));
typedef float f32x4 __attribute__((ext_vector_type(4)));

static __device__ __forceinline__ bf16 f2b(float f) { return __float2bfloat16(f); }
static __device__ __forceinline__ float fast_exp2(float f) { return __builtin_amdgcn_exp2f(f); }

// async global -> LDS, 16B per lane (dest must be wave-uniform base + lane*16)
static __device__ __forceinline__ void gload16(const bf16* g, bf16* l) {
  __builtin_amdgcn_global_load_lds((__attribute__((address_space(1))) const void*)g,
                                   (__attribute__((address_space(3))) void*)l, 16, 0, 0);
}

// ---------------- fp32 -> bf16 linear convert (vectorized) ----------------
__global__ void k_convert(const float* __restrict__ in, bf16* __restrict__ out, int n4) {
  int i = blockIdx.x * blockDim.x + threadIdx.x;
  if (i >= n4) return;
  float4 v = reinterpret_cast<const float4*>(in)[i];
  bf16 o[4] = { f2b(v.x), f2b(v.y), f2b(v.z), f2b(v.w) };
  reinterpret_cast<uint2*>(out)[i] = *reinterpret_cast<uint2*>(o);
}

// ------------- fp32 (R x Cc) -> bf16 transposed (Cc x R) -------------
__global__ void k_transpose(const float* __restrict__ W, bf16* __restrict__ WT, int R, int Cc) {
  __shared__ float tile[32][33];
  int c0 = blockIdx.x * 32, r0 = blockIdx.y * 32;
  int tx = threadIdx.x, ty = threadIdx.y;   // 32 x 8
#pragma unroll
  for (int i = 0; i < 4; ++i)
    tile[ty + 8*i][tx] = W[(size_t)(r0 + ty + 8*i) * Cc + c0 + tx];
  __syncthreads();
#pragma unroll
  for (int i = 0; i < 4; ++i)
    WT[(size_t)(c0 + ty + 8*i) * R + r0 + tx] = f2b(tile[tx][ty + 8*i]);
}

// ------------- per-head V (T x D) -> V^T (D x T), bf16 -------------
__global__ void k_vtrans(const bf16* __restrict__ V, bf16* __restrict__ VT) {
  __shared__ bf16 tile[32][33];
  const int bn = blockIdx.z;
  const int d0 = blockIdx.x * 32, t0 = blockIdx.y * 32;
  const size_t base = (size_t)bn * TT * DHEAD;
  int tx = threadIdx.x, ty = threadIdx.y;   // 32 x 8
#pragma unroll
  for (int i = 0; i < 4; ++i)
    tile[ty + 8*i][tx] = V[base + (size_t)(t0 + ty + 8*i) * DHEAD + d0 + tx];
  __syncthreads();
#pragma unroll
  for (int i = 0; i < 4; ++i)
    VT[base + (size_t)(d0 + ty + 8*i) * TT + t0 + tx] = tile[tx][ty + 8*i];
}

// ---------------- 128x128 bf16 GEMM (m97 structure + XCD swizzle) ----------------
template<int MODE>
__global__ __launch_bounds__(256)
void k_gemm(const bf16* __restrict__ A, const bf16* __restrict__ Bt,
            const float* __restrict__ bias, float* __restrict__ outF,
            bf16* __restrict__ Qb, bf16* __restrict__ Kb, bf16* __restrict__ Vb,
            int K)
{
  const int tid  = threadIdx.x;
  const int wave = tid >> 6, lane = tid & 63;
  const int l16 = lane & 15, l4 = lane >> 4;
  const int wr = wave >> 1, wc = wave & 1;

  // XCD-aware bijective swizzle (grid sizes are multiples of 8)
  const int gx = gridDim.x;
  const int flat = blockIdx.y * gx + blockIdx.x;
  const int cpx = (gx * gridDim.y) >> 3;
  const int swz = (flat & 7) * cpx + (flat >> 3);
  const int bx = swz % gx, by = swz / gx;
  const int m0 = by * 128, n0 = bx * 128;

  __shared__ __align__(16) bf16 As[128*32];   // linear [row][32]
  __shared__ __align__(16) bf16 Bs[128*32];

  f32x4 acc[4][4];
#pragma unroll
  for (int m = 0; m < 4; ++m)
#pragma unroll
    for (int n = 0; n < 4; ++n) acc[m][n] = 0.f;

  const int sr = tid >> 2;            // 0..63
  const int sc = (tid & 3) * 8;       // 0,8,16,24

  for (int k0 = 0; k0 < K; k0 += 32) {
    __syncthreads();
#pragma unroll
    for (int i = 0; i < 2; ++i) {
      gload16(&A [(size_t)(m0 + i*64 + sr) * K + k0 + sc], &As[i*2048 + tid*8]);
      gload16(&Bt[(size_t)(n0 + i*64 + sr) * K + k0 + sc], &Bs[i*2048 + tid*8]);
    }
    __syncthreads();
    bf16x8 af[4], bfr[4];
#pragma unroll
    for (int m = 0; m < 4; ++m)
      af[m] = *reinterpret_cast<const bf16x8*>(&As[(wr*64 + m*16 + l16)*32 + l4*8]);
#pragma unroll
    for (int n = 0; n < 4; ++n)
      bfr[n] = *reinterpret_cast<const bf16x8*>(&Bs[(wc*64 + n*16 + l16)*32 + l4*8]);
#pragma unroll
    for (int m = 0; m < 4; ++m)
#pragma unroll
      for (int n = 0; n < 4; ++n)
        acc[m][n] = __builtin_amdgcn_mfma_f32_16x16x32_bf16(af[m], bfr[n], acc[m][n], 0, 0, 0);
  }

  if (MODE == 0) {
    const int which = n0 >> 10;
    bf16* __restrict__ dst = (which == 0) ? Qb : (which == 1) ? Kb : Vb;
    const float qsc = (which == 0) ? 0.125f * 1.4426950408889634f : 1.0f;
#pragma unroll
    for (int m = 0; m < 4; ++m)
#pragma unroll
      for (int n = 0; n < 4; ++n)
#pragma unroll
        for (int j = 0; j < 4; ++j) {
          int gr = m0 + wr*64 + m*16 + l4*4 + j;
          int gc = n0 + wc*64 + n*16 + l16;
          float val = (acc[m][n][j] + bias[gc]) * qsc;
          int c = gc & (CC-1), head = c >> 6, d = c & 63;
          int b = gr >> 11, t = gr & (TT-1);
          dst[(((size_t)b*NHEAD + head)*TT + t)*DHEAD + d] = f2b(val);
        }
  } else {
#pragma unroll
    for (int m = 0; m < 4; ++m)
#pragma unroll
      for (int n = 0; n < 4; ++n)
#pragma unroll
        for (int j = 0; j < 4; ++j) {
          int gr = m0 + wr*64 + m*16 + l4*4 + j;
          int gc = n0 + wc*64 + n*16 + l16;
          outF[(size_t)gr * CC + gc] = acc[m][n][j] + bias[gc];
        }
  }
}

// ---------------- flash attention v6 ----------------
// KVB=64, double-buffered K/V LDS -> ONE barrier per tile; T14 reg-prefetch;
// swapped-QK in-register softmax, exp2 domain, defer-max; XCD-aware block swizzle.
__global__ __launch_bounds__(256, 4)
void k_attn(const bf16* __restrict__ Qg, const bf16* __restrict__ Kg,
            const bf16* __restrict__ VTg, bf16* __restrict__ Aout)
{
  const int tid  = threadIdx.x;
  const int wave = tid >> 6, lane = tid & 63;
  const int l16 = lane & 15, l4 = lane >> 4;

  // XCD-aware swizzle: 1024 blocks = 8 XCDs x 128; each XCD owns 4 heads
  const int flat = blockIdx.x;
  const int xcd = flat & 7, i6 = flat >> 3;
  const int bn = xcd*4 + (i6 >> 5);          // 0..31 (b*16+h)
  const int q0 = (i6 & 31) * 64;
  const int b = bn >> 4, h = bn & (NHEAD-1);

  __shared__ __align__(16) bf16 Ks[2][KVB][72];     // [buf][kv][d]
  __shared__ __align__(16) bf16 Vt[2][DHEAD][72];   // [buf][d][kv]
  __shared__ __align__(16) bf16 Pl[4][16][72];      // per-wave P[q][kv]

  const size_t hb = (size_t)bn * TT * DHEAD;
  const bf16* __restrict__ Kbase = Kg + hb;
  const bf16* __restrict__ Vbase = VTg + hb;

  bf16x8 qf[2];
#pragma unroll
  for (int kk = 0; kk < 2; ++kk)
    qf[kk] = *reinterpret_cast<const bf16x8*>(
        &Qg[hb + (size_t)(q0 + wave*16 + l16) * DHEAD + kk*32 + l4*8]);

  f32x4 o[4];
#pragma unroll
  for (int n = 0; n < 4; ++n) o[n] = 0.f;
  float mrun = -1e30f, lrun = 0.f;   // per-lane stats for q = l16

  // staging geometry: thread covers 16 elems (2 x bf16x8)
  const int sr = tid >> 2;            // 0..63
  const int sc = (tid & 3) * 16;      // 0,16,32,48

  bf16x8 kreg[2], vreg[2];
#pragma unroll
  for (int i = 0; i < 2; ++i) {
    kreg[i] = *reinterpret_cast<const bf16x8*>(&Kbase[(size_t)sr * DHEAD + sc + 8*i]);
    vreg[i] = *reinterpret_cast<const bf16x8*>(&Vbase[(size_t)sr * TT + sc + 8*i]);
  }
#pragma unroll
  for (int i = 0; i < 2; ++i) {
    *reinterpret_cast<bf16x8*>(&Ks[0][sr][sc + 8*i]) = kreg[i];
    *reinterpret_cast<bf16x8*>(&Vt[0][sr][sc + 8*i]) = vreg[i];
  }

  int cur = 0;
  for (int t0 = 0; t0 < TT; t0 += KVB) {
    const bool more = (t0 + KVB < TT);
    if (more) {                           // T14: issue next-tile loads before the barrier
#pragma unroll
      for (int i = 0; i < 2; ++i) {
        kreg[i] = *reinterpret_cast<const bf16x8*>(
            &Kbase[(size_t)(t0 + KVB + sr) * DHEAD + sc + 8*i]);
        vreg[i] = *reinterpret_cast<const bf16x8*>(
            &Vbase[(size_t)sr * TT + t0 + KVB + sc + 8*i]);
      }
    }
    __syncthreads();                      // buf[cur] visible; prev reads of buf[cur^1] done

    // S^T = K Q^T : lane holds S^T[kv = n*16 + l4*4 + j][q = l16]
    f32x4 s[4];
#pragma unroll
    for (int n = 0; n < 4; ++n) s[n] = 0.f;
    __builtin_amdgcn_s_setprio(1);
#pragma unroll
    for (int n = 0; n < 4; ++n) {
      bf16x8 kf0 = *reinterpret_cast<const bf16x8*>(&Ks[cur][n*16 + l16][l4*8]);
      bf16x8 kf1 = *reinterpret_cast<const bf16x8*>(&Ks[cur][n*16 + l16][32 + l4*8]);
      s[n] = __builtin_amdgcn_mfma_f32_16x16x32_bf16(kf0, qf[0], s[n], 0, 0, 0);
      s[n] = __builtin_amdgcn_mfma_f32_16x16x32_bf16(kf1, qf[1], s[n], 0, 0, 0);
    }
    __builtin_amdgcn_s_setprio(0);

    // --- online softmax (exp2 domain), defer-max THR=8 ---
    float pm = s[0][0];
#pragma unroll
    for (int n = 0; n < 4; ++n)
#pragma unroll
      for (int j = 0; j < 4; ++j) pm = fmaxf(pm, s[n][j]);
    pm = fmaxf(pm, __shfl_xor(pm, 16, 64));
    pm = fmaxf(pm, __shfl_xor(pm, 32, 64));

    if (!__all(pm <= mrun + 8.f)) {
      float mn = fmaxf(mrun, pm);
      float corr = fast_exp2(mrun - mn);
      mrun = mn;
      lrun *= corr;
      float cj[4];
#pragma unroll
      for (int j = 0; j < 4; ++j)
        cj[j] = __shfl(corr, ((lane >> 4) << 2) + j, 64);
#pragma unroll
      for (int n = 0; n < 4; ++n)
#pragma unroll
        for (int j = 0; j < 4; ++j) o[n][j] *= cj[j];
    }

    float psum = 0.f;
#pragma unroll
    for (int n = 0; n < 4; ++n) {
      bf16x4 pk;
#pragma unroll
      for (int j = 0; j < 4; ++j) {
        float pv = fast_exp2(s[n][j] - mrun);
        psum += pv;
        pk[j] = (__bf16)pv;
      }
      *reinterpret_cast<bf16x4*>(&Pl[wave][l16][n*16 + l4*4]) = pk;
    }
    psum += __shfl_xor(psum, 16, 64);
    psum += __shfl_xor(psum, 32, 64);
    lrun += psum;

    // O += P V : A = P[q][kv] (per-wave LDS), B = V^T[d][kv] (LDS)
    bf16x8 pf[2];
#pragma unroll
    for (int kk = 0; kk < 2; ++kk)
      pf[kk] = *reinterpret_cast<const bf16x8*>(&Pl[wave][l16][kk*32 + l4*8]);
    __builtin_amdgcn_s_setprio(1);
#pragma unroll
    for (int n = 0; n < 4; ++n)
#pragma unroll
      for (int kk = 0; kk < 2; ++kk) {
        bf16x8 vf = *reinterpret_cast<const bf16x8*>(&Vt[cur][n*16 + l16][kk*32 + l4*8]);
        o[n] = __builtin_amdgcn_mfma_f32_16x16x32_bf16(pf[kk], vf, o[n], 0, 0, 0);
      }
    __builtin_amdgcn_s_setprio(0);

    if (more) {                           // commit prefetched tile into the other buffer
#pragma unroll
      for (int i = 0; i < 2; ++i) {
        *reinterpret_cast<bf16x8*>(&Ks[cur^1][sr][sc + 8*i]) = kreg[i];
        *reinterpret_cast<bf16x8*>(&Vt[cur^1][sr][sc + 8*i]) = vreg[i];
      }
    }
    cur ^= 1;
  }

  // epilogue
  float linv = 1.0f / lrun;
  float lj[4];
#pragma unroll
  for (int j = 0; j < 4; ++j)
    lj[j] = __shfl(linv, ((lane >> 4) << 2) + j, 64);
#pragma unroll
  for (int j = 0; j < 4; ++j) {
    int gt = q0 + wave*16 + l4*4 + j;
#pragma unroll
    for (int n = 0; n < 4; ++n)
      Aout[((size_t)(b*TT + gt))*CC + h*DHEAD + n*16 + l16] = f2b(o[n][j] * lj[j]);
  }
}

extern "C" void kernel_launch(void* const* d_in, const int* in_sizes, int n_in,
                              void* d_out, int out_size, void* d_ws, size_t ws_size,
                              hipStream_t stream)
{
  const float* x     = (const float*)d_in[0];
  const float* Wqkv  = (const float*)d_in[1];
  const float* bqkv  = (const float*)d_in[2];
  const float* Wproj = (const float*)d_in[3];
  const float* bproj = (const float*)d_in[4];
  float* out = (float*)d_out;

  char* p = (char*)d_ws;
  bf16* Xb     = (bf16*)p;  p += (size_t)MM*CC*2;        // 8 MB (dead after QKV GEMM)
  bf16* WqkvT  = (bf16*)p;  p += (size_t)3*CC*CC*2;      // 6 MB
  bf16* WprojT = (bf16*)p;  p += (size_t)CC*CC*2;        // 2 MB
  bf16* Qb     = (bf16*)p;  p += (size_t)MM*CC*2;        // 8 MB (B,N,T,D)
  bf16* Kb     = (bf16*)p;  p += (size_t)MM*CC*2;        // 8 MB
  bf16* Vb     = (bf16*)p;  p += (size_t)MM*CC*2;        // 8 MB
  bf16* Attn   = (bf16*)p;  p += (size_t)MM*CC*2;        // 8 MB (B,T,C)
  bf16* VTb    = Xb;                                     // reuse Xb: (B,N,D,T)

  k_convert<<<(MM*CC/4 + 255)/256, 256, 0, stream>>>(x, Xb, MM*CC/4);
  k_transpose<<<dim3(3*CC/32, CC/32), dim3(32, 8), 0, stream>>>(Wqkv, WqkvT, CC, 3*CC);
  k_transpose<<<dim3(CC/32, CC/32), dim3(32, 8), 0, stream>>>(Wproj, WprojT, CC, CC);

  k_gemm<0><<<dim3(3*CC/128, MM/128), 256, 0, stream>>>(Xb, WqkvT, bqkv, nullptr, Qb, Kb, Vb, CC);
  k_vtrans<<<dim3(DHEAD/32, TT/32, BB*NHEAD), dim3(32, 8), 0, stream>>>(Vb, VTb);
  k_attn<<<1024, 256, 0, stream>>>(Qb, Kb, VTb, Attn);
  k_gemm<1><<<dim3(CC/128, MM/128), 256, 0, stream>>>(Attn, WprojT, bproj, out, nullptr, nullptr, nullptr, CC);
}

// Round 8
// 160.553 us; speedup vs baseline: 1.1224x; 1.1224x over previous
//
#include <hip/hip_runtime.h>
#include <hip/hip_bf16.h>

#define BB 2
#define TT 2048
#define CC 1024
#define NHEAD 16
#define DHEAD 64
#define MM (BB*TT)
#define KVB 64

using bf16 = __hip_bfloat16;
typedef __bf16 bf16x8 __attribute__((ext_vector_type(8)));
typedef __bf16 bf16x4 __attribute__((ext_vector_type(4)));
typedef float f32x4 __attribute__((ext_vector_type(4)));

static __device__ __forceinline__ bf16 f2b(float f) { return __float2bfloat16(f); }
static __device__ __forceinline__ float fast_exp2(float f) { return __builtin_amdgcn_exp2f(f); }

// async global -> LDS, 16B per lane (dest must be wave-uniform base + lane*16)
static __device__ __forceinline__ void gload16(const bf16* g, bf16* l) {
  __builtin_amdgcn_global_load_lds((__attribute__((address_space(1))) const void*)g,
                                   (__attribute__((address_space(3))) void*)l, 16, 0, 0);
}

// ---------------- fp32 -> bf16 linear convert (vectorized) ----------------
__global__ void k_convert(const float* __restrict__ in, bf16* __restrict__ out, int n4) {
  int i = blockIdx.x * blockDim.x + threadIdx.x;
  if (i >= n4) return;
  float4 v = reinterpret_cast<const float4*>(in)[i];
  bf16 o[4] = { f2b(v.x), f2b(v.y), f2b(v.z), f2b(v.w) };
  reinterpret_cast<uint2*>(out)[i] = *reinterpret_cast<uint2*>(o);
}

// ------------- fp32 (R x Cc) -> bf16 transposed (Cc x R) -------------
__global__ void k_transpose(const float* __restrict__ W, bf16* __restrict__ WT, int R, int Cc) {
  __shared__ float tile[32][33];
  int c0 = blockIdx.x * 32, r0 = blockIdx.y * 32;
  int tx = threadIdx.x, ty = threadIdx.y;   // 32 x 8
#pragma unroll
  for (int i = 0; i < 4; ++i)
    tile[ty + 8*i][tx] = W[(size_t)(r0 + ty + 8*i) * Cc + c0 + tx];
  __syncthreads();
#pragma unroll
  for (int i = 0; i < 4; ++i)
    WT[(size_t)(c0 + ty + 8*i) * R + r0 + tx] = f2b(tile[tx][ty + 8*i]);
}

// ------------- per-head V (T x D) -> V^T (D x T), bf16 -------------
__global__ void k_vtrans(const bf16* __restrict__ V, bf16* __restrict__ VT) {
  __shared__ bf16 tile[32][33];
  const int bn = blockIdx.z;
  const int d0 = blockIdx.x * 32, t0 = blockIdx.y * 32;
  const size_t base = (size_t)bn * TT * DHEAD;
  int tx = threadIdx.x, ty = threadIdx.y;   // 32 x 8
#pragma unroll
  for (int i = 0; i < 4; ++i)
    tile[ty + 8*i][tx] = V[base + (size_t)(t0 + ty + 8*i) * DHEAD + d0 + tx];
  __syncthreads();
#pragma unroll
  for (int i = 0; i < 4; ++i)
    VT[base + (size_t)(d0 + ty + 8*i) * TT + t0 + tx] = tile[tx][ty + 8*i];
}

// ---------------- 128x128 bf16 GEMM (m97 structure + XCD swizzle) ----------------
template<int MODE>
__global__ __launch_bounds__(256)
void k_gemm(const bf16* __restrict__ A, const bf16* __restrict__ Bt,
            const float* __restrict__ bias, float* __restrict__ outF,
            bf16* __restrict__ Qb, bf16* __restrict__ Kb, bf16* __restrict__ Vb,
            int K)
{
  const int tid  = threadIdx.x;
  const int wave = tid >> 6, lane = tid & 63;
  const int l16 = lane & 15, l4 = lane >> 4;
  const int wr = wave >> 1, wc = wave & 1;

  // XCD-aware bijective swizzle (grid sizes are multiples of 8)
  const int gx = gridDim.x;
  const int flat = blockIdx.y * gx + blockIdx.x;
  const int cpx = (gx * gridDim.y) >> 3;
  const int swz = (flat & 7) * cpx + (flat >> 3);
  const int bx = swz % gx, by = swz / gx;
  const int m0 = by * 128, n0 = bx * 128;

  __shared__ __align__(16) bf16 As[128*32];   // linear [row][32]
  __shared__ __align__(16) bf16 Bs[128*32];

  f32x4 acc[4][4];
#pragma unroll
  for (int m = 0; m < 4; ++m)
#pragma unroll
    for (int n = 0; n < 4; ++n) acc[m][n] = 0.f;

  const int sr = tid >> 2;            // 0..63
  const int sc = (tid & 3) * 8;       // 0,8,16,24

  for (int k0 = 0; k0 < K; k0 += 32) {
    __syncthreads();
#pragma unroll
    for (int i = 0; i < 2; ++i) {
      gload16(&A [(size_t)(m0 + i*64 + sr) * K + k0 + sc], &As[i*2048 + tid*8]);
      gload16(&Bt[(size_t)(n0 + i*64 + sr) * K + k0 + sc], &Bs[i*2048 + tid*8]);
    }
    __syncthreads();
    bf16x8 af[4], bfr[4];
#pragma unroll
    for (int m = 0; m < 4; ++m)
      af[m] = *reinterpret_cast<const bf16x8*>(&As[(wr*64 + m*16 + l16)*32 + l4*8]);
#pragma unroll
    for (int n = 0; n < 4; ++n)
      bfr[n] = *reinterpret_cast<const bf16x8*>(&Bs[(wc*64 + n*16 + l16)*32 + l4*8]);
#pragma unroll
    for (int m = 0; m < 4; ++m)
#pragma unroll
      for (int n = 0; n < 4; ++n)
        acc[m][n] = __builtin_amdgcn_mfma_f32_16x16x32_bf16(af[m], bfr[n], acc[m][n], 0, 0, 0);
  }

  if (MODE == 0) {
    const int which = n0 >> 10;
    bf16* __restrict__ dst = (which == 0) ? Qb : (which == 1) ? Kb : Vb;
    const float qsc = (which == 0) ? 0.125f * 1.4426950408889634f : 1.0f;
#pragma unroll
    for (int m = 0; m < 4; ++m)
#pragma unroll
      for (int n = 0; n < 4; ++n)
#pragma unroll
        for (int j = 0; j < 4; ++j) {
          int gr = m0 + wr*64 + m*16 + l4*4 + j;
          int gc = n0 + wc*64 + n*16 + l16;
          float val = (acc[m][n][j] + bias[gc]) * qsc;
          int c = gc & (CC-1), head = c >> 6, d = c & 63;
          int b = gr >> 11, t = gr & (TT-1);
          dst[(((size_t)b*NHEAD + head)*TT + t)*DHEAD + d] = f2b(val);
        }
  } else {
#pragma unroll
    for (int m = 0; m < 4; ++m)
#pragma unroll
      for (int n = 0; n < 4; ++n)
#pragma unroll
        for (int j = 0; j < 4; ++j) {
          int gr = m0 + wr*64 + m*16 + l4*4 + j;
          int gc = n0 + wc*64 + n*16 + l16;
          outF[(size_t)gr * CC + gc] = acc[m][n][j] + bias[gc];
        }
  }
}

// ---------------- flash attention v7 ----------------
// 8 waves / 512 threads, q-tile 128 (wave owns 16 rows); KVB=64 single-buffer,
// R6 inner loop; T14 reg-prefetch; swapped-QK in-register softmax, exp2, defer-max;
// XCD swizzle: 512 blocks = 8 XCDs x 64, each XCD owns 4 heads.
__global__ __launch_bounds__(512, 4)
void k_attn(const bf16* __restrict__ Qg, const bf16* __restrict__ Kg,
            const bf16* __restrict__ VTg, bf16* __restrict__ Aout)
{
  const int tid  = threadIdx.x;
  const int wave = tid >> 6, lane = tid & 63;
  const int l16 = lane & 15, l4 = lane >> 4;

  const int flat = blockIdx.x;               // 0..511
  const int xcd = flat & 7, i6 = flat >> 3;  // i6 = 0..63
  const int bn = xcd*4 + (i6 >> 4);          // 0..31 (b*16+h); 4 heads per XCD
  const int q0 = (i6 & 15) * 128;
  const int b = bn >> 4, h = bn & (NHEAD-1);

  __shared__ __align__(16) bf16 Ks[KVB][72];       // [kv][d]
  __shared__ __align__(16) bf16 Vt[DHEAD][72];     // [d][kv]
  __shared__ __align__(16) bf16 Pl[8][16][72];     // per-wave P[q][kv]

  const size_t hb = (size_t)bn * TT * DHEAD;
  const bf16* __restrict__ Kbase = Kg + hb;
  const bf16* __restrict__ Vbase = VTg + hb;

  bf16x8 qf[2];
#pragma unroll
  for (int kk = 0; kk < 2; ++kk)
    qf[kk] = *reinterpret_cast<const bf16x8*>(
        &Qg[hb + (size_t)(q0 + wave*16 + l16) * DHEAD + kk*32 + l4*8]);

  f32x4 o[4];
#pragma unroll
  for (int n = 0; n < 4; ++n) o[n] = 0.f;
  float mrun = -1e30f, lrun = 0.f;   // per-lane stats for q = l16 (replicated across l4)

  // staging geometry: 512 threads x 8 elems = one 64x64 tile each for K and V^T
  const int sr = tid >> 3;            // 0..63
  const int sc = (tid & 7) * 8;       // 0..56

  bf16x8 kreg, vreg;
  kreg = *reinterpret_cast<const bf16x8*>(&Kbase[(size_t)sr * DHEAD + sc]);
  vreg = *reinterpret_cast<const bf16x8*>(&Vbase[(size_t)sr * TT + sc]);
  *reinterpret_cast<bf16x8*>(&Ks[sr][sc]) = kreg;
  *reinterpret_cast<bf16x8*>(&Vt[sr][sc]) = vreg;

  for (int t0 = 0; t0 < TT; t0 += KVB) {
    __syncthreads();                      // tile t0 visible in LDS
    const bool more = (t0 + KVB < TT);
    if (more) {                           // T14: issue next-tile loads now, commit later
      kreg = *reinterpret_cast<const bf16x8*>(&Kbase[(size_t)(t0 + KVB + sr) * DHEAD + sc]);
      vreg = *reinterpret_cast<const bf16x8*>(&Vbase[(size_t)sr * TT + t0 + KVB + sc]);
    }

    // S^T = K Q^T : lane holds S^T[kv = n*16 + l4*4 + j][q = l16]
    f32x4 s[4];
#pragma unroll
    for (int n = 0; n < 4; ++n) s[n] = 0.f;
    __builtin_amdgcn_s_setprio(1);
#pragma unroll
    for (int n = 0; n < 4; ++n) {
      bf16x8 kf0 = *reinterpret_cast<const bf16x8*>(&Ks[n*16 + l16][l4*8]);
      bf16x8 kf1 = *reinterpret_cast<const bf16x8*>(&Ks[n*16 + l16][32 + l4*8]);
      s[n] = __builtin_amdgcn_mfma_f32_16x16x32_bf16(kf0, qf[0], s[n], 0, 0, 0);
      s[n] = __builtin_amdgcn_mfma_f32_16x16x32_bf16(kf1, qf[1], s[n], 0, 0, 0);
    }
    __builtin_amdgcn_s_setprio(0);

    // --- online softmax (exp2 domain), defer-max THR=8 ---
    float pm = s[0][0];
#pragma unroll
    for (int n = 0; n < 4; ++n)
#pragma unroll
      for (int j = 0; j < 4; ++j) pm = fmaxf(pm, s[n][j]);
    pm = fmaxf(pm, __shfl_xor(pm, 16, 64));
    pm = fmaxf(pm, __shfl_xor(pm, 32, 64));

    if (!__all(pm <= mrun + 8.f)) {
      float mn = fmaxf(mrun, pm);
      float corr = fast_exp2(mrun - mn);
      mrun = mn;
      lrun *= corr;
      float cj[4];
#pragma unroll
      for (int j = 0; j < 4; ++j)
        cj[j] = __shfl(corr, ((lane >> 4) << 2) + j, 64);
#pragma unroll
      for (int n = 0; n < 4; ++n)
#pragma unroll
        for (int j = 0; j < 4; ++j) o[n][j] *= cj[j];
    }

    float psum = 0.f;
#pragma unroll
    for (int n = 0; n < 4; ++n) {
      bf16x4 pk;
#pragma unroll
      for (int j = 0; j < 4; ++j) {
        float pv = fast_exp2(s[n][j] - mrun);
        psum += pv;
        pk[j] = (__bf16)pv;
      }
      *reinterpret_cast<bf16x4*>(&Pl[wave][l16][n*16 + l4*4]) = pk;
    }
    psum += __shfl_xor(psum, 16, 64);
    psum += __shfl_xor(psum, 32, 64);
    lrun += psum;

    // O += P V : A = P[q][kv] (per-wave LDS), B = V^T[d][kv] (LDS)
    bf16x8 pf[2];
#pragma unroll
    for (int kk = 0; kk < 2; ++kk)
      pf[kk] = *reinterpret_cast<const bf16x8*>(&Pl[wave][l16][kk*32 + l4*8]);
    __builtin_amdgcn_s_setprio(1);
#pragma unroll
    for (int n = 0; n < 4; ++n)
#pragma unroll
      for (int kk = 0; kk < 2; ++kk) {
        bf16x8 vf = *reinterpret_cast<const bf16x8*>(&Vt[n*16 + l16][kk*32 + l4*8]);
        o[n] = __builtin_amdgcn_mfma_f32_16x16x32_bf16(pf[kk], vf, o[n], 0, 0, 0);
      }
    __builtin_amdgcn_s_setprio(0);

    __syncthreads();                      // all waves done reading Ks/Vt
    if (more) {
      *reinterpret_cast<bf16x8*>(&Ks[sr][sc]) = kreg;
      *reinterpret_cast<bf16x8*>(&Vt[sr][sc]) = vreg;
    }
  }

  // epilogue
  float linv = 1.0f / lrun;
  float lj[4];
#pragma unroll
  for (int j = 0; j < 4; ++j)
    lj[j] = __shfl(linv, ((lane >> 4) << 2) + j, 64);
#pragma unroll
  for (int j = 0; j < 4; ++j) {
    int gt = q0 + wave*16 + l4*4 + j;
#pragma unroll
    for (int n = 0; n < 4; ++n)
      Aout[((size_t)(b*TT + gt))*CC + h*DHEAD + n*16 + l16] = f2b(o[n][j] * lj[j]);
  }
}

extern "C" void kernel_launch(void* const* d_in, const int* in_sizes, int n_in,
                              void* d_out, int out_size, void* d_ws, size_t ws_size,
                              hipStream_t stream)
{
  const float* x     = (const float*)d_in[0];
  const float* Wqkv  = (const float*)d_in[1];
  const float* bqkv  = (const float*)d_in[2];
  const float* Wproj = (const float*)d_in[3];
  const float* bproj = (const float*)d_in[4];
  float* out = (float*)d_out;

  char* p = (char*)d_ws;
  bf16* Xb     = (bf16*)p;  p += (size_t)MM*CC*2;        // 8 MB (dead after QKV GEMM)
  bf16* WqkvT  = (bf16*)p;  p += (size_t)3*CC*CC*2;      // 6 MB
  bf16* WprojT = (bf16*)p;  p += (size_t)CC*CC*2;        // 2 MB
  bf16* Qb     = (bf16*)p;  p += (size_t)MM*CC*2;        // 8 MB (B,N,T,D)
  bf16* Kb     = (bf16*)p;  p += (size_t)MM*CC*2;        // 8 MB
  bf16* Vb     = (bf16*)p;  p += (size_t)MM*CC*2;        // 8 MB
  bf16* Attn   = (bf16*)p;  p += (size_t)MM*CC*2;        // 8 MB (B,T,C)
  bf16* VTb    = Xb;                                     // reuse Xb: (B,N,D,T)

  k_convert<<<(MM*CC/4 + 255)/256, 256, 0, stream>>>(x, Xb, MM*CC/4);
  k_transpose<<<dim3(3*CC/32, CC/32), dim3(32, 8), 0, stream>>>(Wqkv, WqkvT, CC, 3*CC);
  k_transpose<<<dim3(CC/32, CC/32), dim3(32, 8), 0, stream>>>(Wproj, WprojT, CC, CC);

  k_gemm<0><<<dim3(3*CC/128, MM/128), 256, 0, stream>>>(Xb, WqkvT, bqkv, nullptr, Qb, Kb, Vb, CC);
  k_vtrans<<<dim3(DHEAD/32, TT/32, BB*NHEAD), dim3(32, 8), 0, stream>>>(Vb, VTb);
  k_attn<<<512, 512, 0, stream>>>(Qb, Kb, VTb, Attn);
  k_gemm<1><<<dim3(CC/128, MM/128), 256, 0, stream>>>(Attn, WprojT, bproj, out, nullptr, nullptr, nullptr, CC);
}

// Round 9
// 154.093 us; speedup vs baseline: 1.1695x; 1.0419x over previous
//
#include <hip/hip_runtime.h>
#include <hip/hip_bf16.h>

#define BB 2
#define TT 2048
#define CC 1024
#define NHEAD 16
#define DHEAD 64
#define MM (BB*TT)
#define KVB 128

using bf16 = __hip_bfloat16;
typedef __bf16 bf16x8 __attribute__((ext_vector_type(8)));
typedef __bf16 bf16x4 __attribute__((ext_vector_type(4)));
typedef float f32x4 __attribute__((ext_vector_type(4)));

static __device__ __forceinline__ bf16 f2b(float f) { return __float2bfloat16(f); }
static __device__ __forceinline__ float fast_exp2(float f) { return __builtin_amdgcn_exp2f(f); }

// async global -> LDS, 16B per lane (dest must be wave-uniform base + lane*16)
static __device__ __forceinline__ void gload16(const bf16* g, bf16* l) {
  __builtin_amdgcn_global_load_lds((__attribute__((address_space(1))) const void*)g,
                                   (__attribute__((address_space(3))) void*)l, 16, 0, 0);
}

// ------------- fused prep: x->bf16 convert + Wqkv^T + Wproj^T -------------
// grid regions: [0,4096) convert (256 thr x 4 float4), [4096,7168) Wqkv 32x32 tiles,
// [7168,8192) Wproj 32x32 tiles.
__global__ __launch_bounds__(256)
void k_prep(const float* __restrict__ x, bf16* __restrict__ Xb,
            const float* __restrict__ Wqkv, bf16* __restrict__ WqkvT,
            const float* __restrict__ Wproj, bf16* __restrict__ WprojT)
{
  const int bid = blockIdx.x, tid = threadIdx.x;
  if (bid < 4096) {
    int i = bid * 256 + tid;
    float4 v = reinterpret_cast<const float4*>(x)[i];
    bf16 o[4] = { f2b(v.x), f2b(v.y), f2b(v.z), f2b(v.w) };
    reinterpret_cast<uint2*>(Xb)[i] = *reinterpret_cast<uint2*>(o);
    return;
  }
  __shared__ float tile[32][33];
  const float* W; bf16* WT; int R, Cc, bx, by;
  if (bid < 4096 + 3072) {
    int b2 = bid - 4096;  W = Wqkv;  WT = WqkvT;  R = CC; Cc = 3*CC;
    bx = b2 % 96; by = b2 / 96;
  } else {
    int b3 = bid - 7168;  W = Wproj; WT = WprojT; R = CC; Cc = CC;
    bx = b3 % 32; by = b3 / 32;
  }
  int c0 = bx * 32, r0 = by * 32;
  int tx = tid & 31, ty = tid >> 5;   // 32 x 8
#pragma unroll
  for (int i = 0; i < 4; ++i)
    tile[ty + 8*i][tx] = W[(size_t)(r0 + ty + 8*i) * Cc + c0 + tx];
  __syncthreads();
#pragma unroll
  for (int i = 0; i < 4; ++i)
    WT[(size_t)(c0 + ty + 8*i) * R + r0 + tx] = f2b(tile[tx][ty + 8*i]);
}

// ------------- per-head V (T x D) -> V^T (D x T), bf16 -------------
__global__ void k_vtrans(const bf16* __restrict__ V, bf16* __restrict__ VT) {
  __shared__ bf16 tile[32][33];
  const int bn = blockIdx.z;
  const int d0 = blockIdx.x * 32, t0 = blockIdx.y * 32;
  const size_t base = (size_t)bn * TT * DHEAD;
  int tx = threadIdx.x, ty = threadIdx.y;   // 32 x 8
#pragma unroll
  for (int i = 0; i < 4; ++i)
    tile[ty + 8*i][tx] = V[base + (size_t)(t0 + ty + 8*i) * DHEAD + d0 + tx];
  __syncthreads();
#pragma unroll
  for (int i = 0; i < 4; ++i)
    VT[base + (size_t)(d0 + ty + 8*i) * TT + t0 + tx] = tile[tx][ty + 8*i];
}

// ---------------- 128x128 bf16 GEMM (m97 structure + XCD swizzle) ----------------
template<int MODE>
__global__ __launch_bounds__(256)
void k_gemm(const bf16* __restrict__ A, const bf16* __restrict__ Bt,
            const float* __restrict__ bias, float* __restrict__ outF,
            bf16* __restrict__ Qb, bf16* __restrict__ Kb, bf16* __restrict__ Vb,
            int K)
{
  const int tid  = threadIdx.x;
  const int wave = tid >> 6, lane = tid & 63;
  const int l16 = lane & 15, l4 = lane >> 4;
  const int wr = wave >> 1, wc = wave & 1;

  // XCD-aware bijective swizzle (grid sizes are multiples of 8)
  const int gx = gridDim.x;
  const int flat = blockIdx.y * gx + blockIdx.x;
  const int cpx = (gx * gridDim.y) >> 3;
  const int swz = (flat & 7) * cpx + (flat >> 3);
  const int bx = swz % gx, by = swz / gx;
  const int m0 = by * 128, n0 = bx * 128;

  __shared__ __align__(16) bf16 As[128*32];   // linear [row][32]
  __shared__ __align__(16) bf16 Bs[128*32];

  f32x4 acc[4][4];
#pragma unroll
  for (int m = 0; m < 4; ++m)
#pragma unroll
    for (int n = 0; n < 4; ++n) acc[m][n] = 0.f;

  const int sr = tid >> 2;            // 0..63
  const int sc = (tid & 3) * 8;       // 0,8,16,24

  for (int k0 = 0; k0 < K; k0 += 32) {
    __syncthreads();
#pragma unroll
    for (int i = 0; i < 2; ++i) {
      gload16(&A [(size_t)(m0 + i*64 + sr) * K + k0 + sc], &As[i*2048 + tid*8]);
      gload16(&Bt[(size_t)(n0 + i*64 + sr) * K + k0 + sc], &Bs[i*2048 + tid*8]);
    }
    __syncthreads();
    bf16x8 af[4], bfr[4];
#pragma unroll
    for (int m = 0; m < 4; ++m)
      af[m] = *reinterpret_cast<const bf16x8*>(&As[(wr*64 + m*16 + l16)*32 + l4*8]);
#pragma unroll
    for (int n = 0; n < 4; ++n)
      bfr[n] = *reinterpret_cast<const bf16x8*>(&Bs[(wc*64 + n*16 + l16)*32 + l4*8]);
#pragma unroll
    for (int m = 0; m < 4; ++m)
#pragma unroll
      for (int n = 0; n < 4; ++n)
        acc[m][n] = __builtin_amdgcn_mfma_f32_16x16x32_bf16(af[m], bfr[n], acc[m][n], 0, 0, 0);
  }

  if (MODE == 0) {
    const int which = n0 >> 10;
    bf16* __restrict__ dst = (which == 0) ? Qb : (which == 1) ? Kb : Vb;
    const float qsc = (which == 0) ? 0.125f * 1.4426950408889634f : 1.0f;
#pragma unroll
    for (int m = 0; m < 4; ++m)
#pragma unroll
      for (int n = 0; n < 4; ++n)
#pragma unroll
        for (int j = 0; j < 4; ++j) {
          int gr = m0 + wr*64 + m*16 + l4*4 + j;
          int gc = n0 + wc*64 + n*16 + l16;
          float val = (acc[m][n][j] + bias[gc]) * qsc;
          int c = gc & (CC-1), head = c >> 6, d = c & 63;
          int b = gr >> 11, t = gr & (TT-1);
          dst[(((size_t)b*NHEAD + head)*TT + t)*DHEAD + d] = f2b(val);
        }
  } else {
#pragma unroll
    for (int m = 0; m < 4; ++m)
#pragma unroll
      for (int n = 0; n < 4; ++n)
#pragma unroll
        for (int j = 0; j < 4; ++j) {
          int gr = m0 + wr*64 + m*16 + l4*4 + j;
          int gc = n0 + wc*64 + n*16 + l16;
          outF[(size_t)gr * CC + gc] = acc[m][n][j] + bias[gc];
        }
  }
}

// ---------------- flash attention v8 ----------------
// 8 waves / 512 threads, q-tile 128, KVB=128 (one softmax pass per 128 kv);
// single-buffer, 2 barriers per tile; T14 reg-prefetch; swapped-QK in-register
// softmax, exp2 domain, defer-max; XCD swizzle (512 = 8 x 64, 4 heads per XCD).
// LDS 70.6 KB -> exactly 2 blocks/CU = grid demand (occupancy preserved).
__global__ __launch_bounds__(512, 2)
void k_attn(const bf16* __restrict__ Qg, const bf16* __restrict__ Kg,
            const bf16* __restrict__ VTg, bf16* __restrict__ Aout)
{
  const int tid  = threadIdx.x;
  const int wave = tid >> 6, lane = tid & 63;
  const int l16 = lane & 15, l4 = lane >> 4;

  const int flat = blockIdx.x;               // 0..511
  const int xcd = flat & 7, i6 = flat >> 3;  // i6 = 0..63
  const int bn = xcd*4 + (i6 >> 4);          // 0..31 (b*16+h); 4 heads per XCD
  const int q0 = (i6 & 15) * 128;
  const int b = bn >> 4, h = bn & (NHEAD-1);

  __shared__ __align__(16) bf16 Ks[KVB][72];       // [kv][d]   18.4 KB
  __shared__ __align__(16) bf16 Vt[DHEAD][136];    // [d][kv]   17.4 KB
  __shared__ __align__(16) bf16 Pl[8][16][136];    // per-wave P[q][kv]  34.8 KB

  const size_t hb = (size_t)bn * TT * DHEAD;
  const bf16* __restrict__ Kbase = Kg + hb;
  const bf16* __restrict__ Vbase = VTg + hb;

  bf16x8 qf[2];
#pragma unroll
  for (int kk = 0; kk < 2; ++kk)
    qf[kk] = *reinterpret_cast<const bf16x8*>(
        &Qg[hb + (size_t)(q0 + wave*16 + l16) * DHEAD + kk*32 + l4*8]);

  f32x4 o[4];
#pragma unroll
  for (int n = 0; n < 4; ++n) o[n] = 0.f;
  float mrun = -1e30f, lrun = 0.f;   // per-lane stats for q = l16 (replicated across l4)

  // staging geometry: K 128x64 (thread: row tid>>2, 16 cols), V^T 64x128 (row tid>>3, 16 cols)
  const int krow = tid >> 2, kcol = (tid & 3) * 16;
  const int vrow = tid >> 3, vcol = (tid & 7) * 16;

  bf16x8 kreg[2], vreg[2];
#pragma unroll
  for (int i = 0; i < 2; ++i) {
    kreg[i] = *reinterpret_cast<const bf16x8*>(&Kbase[(size_t)krow * DHEAD + kcol + 8*i]);
    vreg[i] = *reinterpret_cast<const bf16x8*>(&Vbase[(size_t)vrow * TT + vcol + 8*i]);
  }
#pragma unroll
  for (int i = 0; i < 2; ++i) {
    *reinterpret_cast<bf16x8*>(&Ks[krow][kcol + 8*i]) = kreg[i];
    *reinterpret_cast<bf16x8*>(&Vt[vrow][vcol + 8*i]) = vreg[i];
  }

  for (int t0 = 0; t0 < TT; t0 += KVB) {
    __syncthreads();                      // tile t0 visible in LDS
    const bool more = (t0 + KVB < TT);
    if (more) {                           // T14: issue next-tile loads now, commit later
#pragma unroll
      for (int i = 0; i < 2; ++i) {
        kreg[i] = *reinterpret_cast<const bf16x8*>(
            &Kbase[(size_t)(t0 + KVB + krow) * DHEAD + kcol + 8*i]);
        vreg[i] = *reinterpret_cast<const bf16x8*>(
            &Vbase[(size_t)vrow * TT + t0 + KVB + vcol + 8*i]);
      }
    }

    // S^T = K Q^T : lane holds S^T[kv = n*16 + l4*4 + j][q = l16], n = 0..7
    f32x4 s[8];
#pragma unroll
    for (int n = 0; n < 8; ++n) s[n] = 0.f;
    __builtin_amdgcn_s_setprio(1);
#pragma unroll
    for (int n = 0; n < 8; ++n) {
      bf16x8 kf0 = *reinterpret_cast<const bf16x8*>(&Ks[n*16 + l16][l4*8]);
      bf16x8 kf1 = *reinterpret_cast<const bf16x8*>(&Ks[n*16 + l16][32 + l4*8]);
      s[n] = __builtin_amdgcn_mfma_f32_16x16x32_bf16(kf0, qf[0], s[n], 0, 0, 0);
      s[n] = __builtin_amdgcn_mfma_f32_16x16x32_bf16(kf1, qf[1], s[n], 0, 0, 0);
    }
    __builtin_amdgcn_s_setprio(0);

    // --- online softmax over 128 kv (exp2 domain), defer-max THR=8 ---
    float pm = s[0][0];
#pragma unroll
    for (int n = 0; n < 8; ++n)
#pragma unroll
      for (int j = 0; j < 4; ++j) pm = fmaxf(pm, s[n][j]);
    pm = fmaxf(pm, __shfl_xor(pm, 16, 64));
    pm = fmaxf(pm, __shfl_xor(pm, 32, 64));

    if (!__all(pm <= mrun + 8.f)) {
      float mn = fmaxf(mrun, pm);
      float corr = fast_exp2(mrun - mn);
      mrun = mn;
      lrun *= corr;
      float cj[4];
#pragma unroll
      for (int j = 0; j < 4; ++j)
        cj[j] = __shfl(corr, ((lane >> 4) << 2) + j, 64);
#pragma unroll
      for (int n = 0; n < 4; ++n)
#pragma unroll
        for (int j = 0; j < 4; ++j) o[n][j] *= cj[j];
    }

    float psum = 0.f;
#pragma unroll
    for (int n = 0; n < 8; ++n) {
      bf16x4 pk;
#pragma unroll
      for (int j = 0; j < 4; ++j) {
        float pv = fast_exp2(s[n][j] - mrun);
        psum += pv;
        pk[j] = (__bf16)pv;
      }
      *reinterpret_cast<bf16x4*>(&Pl[wave][l16][n*16 + l4*4]) = pk;
    }
    psum += __shfl_xor(psum, 16, 64);
    psum += __shfl_xor(psum, 32, 64);
    lrun += psum;

    // O += P V : A = P[q][kv] (per-wave LDS), B = V^T[d][kv] (LDS)
    bf16x8 pf[4];
#pragma unroll
    for (int kk = 0; kk < 4; ++kk)
      pf[kk] = *reinterpret_cast<const bf16x8*>(&Pl[wave][l16][kk*32 + l4*8]);
    __builtin_amdgcn_s_setprio(1);
#pragma unroll
    for (int n = 0; n < 4; ++n)
#pragma unroll
      for (int kk = 0; kk < 4; ++kk) {
        bf16x8 vf = *reinterpret_cast<const bf16x8*>(&Vt[n*16 + l16][kk*32 + l4*8]);
        o[n] = __builtin_amdgcn_mfma_f32_16x16x32_bf16(pf[kk], vf, o[n], 0, 0, 0);
      }
    __builtin_amdgcn_s_setprio(0);

    __syncthreads();                      // all waves done reading Ks/Vt
    if (more) {
#pragma unroll
      for (int i = 0; i < 2; ++i) {
        *reinterpret_cast<bf16x8*>(&Ks[krow][kcol + 8*i]) = kreg[i];
        *reinterpret_cast<bf16x8*>(&Vt[vrow][vcol + 8*i]) = vreg[i];
      }
    }
  }

  // epilogue
  float linv = 1.0f / lrun;
  float lj[4];
#pragma unroll
  for (int j = 0; j < 4; ++j)
    lj[j] = __shfl(linv, ((lane >> 4) << 2) + j, 64);
#pragma unroll
  for (int j = 0; j < 4; ++j) {
    int gt = q0 + wave*16 + l4*4 + j;
#pragma unroll
    for (int n = 0; n < 4; ++n)
      Aout[((size_t)(b*TT + gt))*CC + h*DHEAD + n*16 + l16] = f2b(o[n][j] * lj[j]);
  }
}

extern "C" void kernel_launch(void* const* d_in, const int* in_sizes, int n_in,
                              void* d_out, int out_size, void* d_ws, size_t ws_size,
                              hipStream_t stream)
{
  const float* x     = (const float*)d_in[0];
  const float* Wqkv  = (const float*)d_in[1];
  const float* bqkv  = (const float*)d_in[2];
  const float* Wproj = (const float*)d_in[3];
  const float* bproj = (const float*)d_in[4];
  float* out = (float*)d_out;

  char* p = (char*)d_ws;
  bf16* Xb     = (bf16*)p;  p += (size_t)MM*CC*2;        // 8 MB (dead after QKV GEMM)
  bf16* WqkvT  = (bf16*)p;  p += (size_t)3*CC*CC*2;      // 6 MB
  bf16* WprojT = (bf16*)p;  p += (size_t)CC*CC*2;        // 2 MB
  bf16* Qb     = (bf16*)p;  p += (size_t)MM*CC*2;        // 8 MB (B,N,T,D)
  bf16* Kb     = (bf16*)p;  p += (size_t)MM*CC*2;        // 8 MB
  bf16* Vb     = (bf16*)p;  p += (size_t)MM*CC*2;        // 8 MB
  bf16* Attn   = (bf16*)p;  p += (size_t)MM*CC*2;        // 8 MB (B,T,C)
  bf16* VTb    = Xb;                                     // reuse Xb: (B,N,D,T)

  k_prep<<<8192, 256, 0, stream>>>(x, Xb, Wqkv, WqkvT, Wproj, WprojT);
  k_gemm<0><<<dim3(3*CC/128, MM/128), 256, 0, stream>>>(Xb, WqkvT, bqkv, nullptr, Qb, Kb, Vb, CC);
  k_vtrans<<<dim3(DHEAD/32, TT/32, BB*NHEAD), dim3(32, 8), 0, stream>>>(Vb, VTb);
  k_attn<<<512, 512, 0, stream>>>(Qb, Kb, VTb, Attn);
  k_gemm<1><<<dim3(CC/128, MM/128), 256, 0, stream>>>(Attn, WprojT, bproj, out, nullptr, nullptr, nullptr, CC);
}

// Round 10
// 136.585 us; speedup vs baseline: 1.3194x; 1.1282x over previous
//
#include <hip/hip_runtime.h>
#include <hip/hip_bf16.h>

#define BB 2
#define TT 2048
#define CC 1024
#define NHEAD 16
#define DHEAD 64
#define MM (BB*TT)
#define KVB 128

using bf16 = __hip_bfloat16;
typedef __bf16 bf16x8 __attribute__((ext_vector_type(8)));
typedef __bf16 bf16x4 __attribute__((ext_vector_type(4)));
typedef float f32x4 __attribute__((ext_vector_type(4)));

static __device__ __forceinline__ bf16 f2b(float f) { return __float2bfloat16(f); }
static __device__ __forceinline__ float fast_exp2(float f) { return __builtin_amdgcn_exp2f(f); }

// async global -> LDS, 16B per lane (dest wave-uniform base; HW adds lane*16B)
static __device__ __forceinline__ void gload16(const bf16* g, bf16* l) {
  __builtin_amdgcn_global_load_lds((__attribute__((address_space(1))) const void*)g,
                                   (__attribute__((address_space(3))) void*)l, 16, 0, 0);
}

// ------------- fused prep: x->bf16 convert + Wqkv^T + Wproj^T -------------
__global__ __launch_bounds__(256)
void k_prep(const float* __restrict__ x, bf16* __restrict__ Xb,
            const float* __restrict__ Wqkv, bf16* __restrict__ WqkvT,
            const float* __restrict__ Wproj, bf16* __restrict__ WprojT)
{
  const int bid = blockIdx.x, tid = threadIdx.x;
  if (bid < 4096) {
    int i = bid * 256 + tid;
    float4 v = reinterpret_cast<const float4*>(x)[i];
    bf16 o[4] = { f2b(v.x), f2b(v.y), f2b(v.z), f2b(v.w) };
    reinterpret_cast<uint2*>(Xb)[i] = *reinterpret_cast<uint2*>(o);
    return;
  }
  __shared__ float tile[32][33];
  const float* W; bf16* WT; int R, Cc, bx, by;
  if (bid < 4096 + 3072) {
    int b2 = bid - 4096;  W = Wqkv;  WT = WqkvT;  R = CC; Cc = 3*CC;
    bx = b2 % 96; by = b2 / 96;
  } else {
    int b3 = bid - 7168;  W = Wproj; WT = WprojT; R = CC; Cc = CC;
    bx = b3 % 32; by = b3 / 32;
  }
  int c0 = bx * 32, r0 = by * 32;
  int tx = tid & 31, ty = tid >> 5;   // 32 x 8
#pragma unroll
  for (int i = 0; i < 4; ++i)
    tile[ty + 8*i][tx] = W[(size_t)(r0 + ty + 8*i) * Cc + c0 + tx];
  __syncthreads();
#pragma unroll
  for (int i = 0; i < 4; ++i)
    WT[(size_t)(c0 + ty + 8*i) * R + r0 + tx] = f2b(tile[tx][ty + 8*i]);
}

// ------------- per-head V (T x D) -> V^T (D x T), bf16 -------------
__global__ void k_vtrans(const bf16* __restrict__ V, bf16* __restrict__ VT) {
  __shared__ bf16 tile[32][33];
  const int bn = blockIdx.z;
  const int d0 = blockIdx.x * 32, t0 = blockIdx.y * 32;
  const size_t base = (size_t)bn * TT * DHEAD;
  int tx = threadIdx.x, ty = threadIdx.y;   // 32 x 8
#pragma unroll
  for (int i = 0; i < 4; ++i)
    tile[ty + 8*i][tx] = V[base + (size_t)(t0 + ty + 8*i) * DHEAD + d0 + tx];
  __syncthreads();
#pragma unroll
  for (int i = 0; i < 4; ++i)
    VT[base + (size_t)(d0 + ty + 8*i) * TT + t0 + tx] = tile[tx][ty + 8*i];
}

// ============ QKV GEMM: 256x256 tile, BK=32, dbuf LDS + counted vmcnt ============
// 8 waves (2Mx4N), per-wave 128x64 output, 32 MFMA/wave per K-tile.
// LDS 64KB: [buf][A 8192 elem | B 8192 elem], halves of 4096 elem (128 rows x 32).
// Swizzle: 16B slot s stored at s ^ ((row>>1)&3) -> 2-way (free) frag reads.
// Staged via global_load_lds with pre-swizzled SOURCE address (linear LDS dest).
#define NTK 32
__global__ __launch_bounds__(512, 1)
void k_gemm_qkv(const bf16* __restrict__ Ag, const bf16* __restrict__ Bg,
                const float* __restrict__ bias,
                bf16* __restrict__ Qb, bf16* __restrict__ Kb, bf16* __restrict__ Vb)
{
  const int tid = threadIdx.x;
  const int w = tid >> 6, l = tid & 63;
  const int l16 = l & 15, l4 = l >> 4;
  const int wr = w >> 2, wc = w & 3;          // 2 x 4 wave grid

  // XCD swizzle: 192 blocks = 8 XCDs x 24; column-major chunks (B-panel hot in L2)
  const int flat = blockIdx.x;
  const int swz = (flat & 7) * 24 + (flat >> 3);
  const int bx = swz / 16, by = swz % 16;     // bx 0..11, by 0..15
  const int m0 = by * 256, n0 = bx * 256;

  __shared__ __align__(16) bf16 sm[32768];    // 64KB

  f32x4 acc[8][4];
#pragma unroll
  for (int m = 0; m < 8; ++m)
#pragma unroll
    for (int n = 0; n < 4; ++n) acc[m][n] = 0.f;

  // staging geometry (per thread, one gload16 per half-tile):
  // LDS dest chunk = halfbase + w*512 (uniform); lane lands at +l*8 elems
  // -> row r = tid>>2 (0..127), linear slot = tid&3; source slot = (tid&3)^((tid>>3)&3)
  const int srow = tid >> 2;
  const int scol = ((tid & 3) ^ ((tid >> 3) & 3)) * 8;

#define STAGE(buf, kt) do {                                                          \
    const int kb = (kt) * 32 + scol;                                                 \
    gload16(&Ag[(size_t)(m0 +       srow) * CC + kb], &sm[(buf)*16384         + w*512]); \
    gload16(&Ag[(size_t)(m0 + 128 + srow) * CC + kb], &sm[(buf)*16384 +  4096 + w*512]); \
    gload16(&Bg[(size_t)(n0 +       srow) * CC + kb], &sm[(buf)*16384 +  8192 + w*512]); \
    gload16(&Bg[(size_t)(n0 + 128 + srow) * CC + kb], &sm[(buf)*16384 + 12288 + w*512]); \
  } while (0)

  STAGE(0, 0);
  STAGE(1, 1);
  asm volatile("s_waitcnt vmcnt(4)" ::: "memory");   // tile0's 4 loads done
  __builtin_amdgcn_s_barrier();

  const int slotA = (l4 ^ ((l16 >> 1) & 3)) * 8;     // swizzled 8-elem slot offset
  const int aoff = wr * 4096 + l16 * 32 + slotA;     // + mf*512
  const int boff = 8192 + (wc >> 1) * 4096 + ((wc & 1) * 64 + l16) * 32 + slotA;  // + nf*512

  for (int kt = 0; kt < NTK; ++kt) {
    const int buf = kt & 1;
    const int base = buf * 16384;

    bf16x8 bfr[4], af[4];
#pragma unroll
    for (int n = 0; n < 4; ++n)
      bfr[n] = *reinterpret_cast<const bf16x8*>(&sm[base + boff + n*512]);
#pragma unroll
    for (int m = 0; m < 4; ++m)
      af[m] = *reinterpret_cast<const bf16x8*>(&sm[base + aoff + m*512]);
    __builtin_amdgcn_s_setprio(1);
#pragma unroll
    for (int m = 0; m < 4; ++m)
#pragma unroll
      for (int n = 0; n < 4; ++n)
        acc[m][n] = __builtin_amdgcn_mfma_f32_16x16x32_bf16(af[m], bfr[n], acc[m][n], 0, 0, 0);
    __builtin_amdgcn_s_setprio(0);
#pragma unroll
    for (int m = 0; m < 4; ++m)
      af[m] = *reinterpret_cast<const bf16x8*>(&sm[base + aoff + (m+4)*512]);
    __builtin_amdgcn_s_setprio(1);
#pragma unroll
    for (int m = 0; m < 4; ++m)
#pragma unroll
      for (int n = 0; n < 4; ++n)
        acc[m+4][n] = __builtin_amdgcn_mfma_f32_16x16x32_bf16(af[m], bfr[n], acc[m+4][n], 0, 0, 0);
    __builtin_amdgcn_s_setprio(0);

    __builtin_amdgcn_s_barrier();            // all waves done reading buf
    if (kt + 2 < NTK) {
      STAGE(buf, kt + 2);                    // overwrite buf with tile kt+2
      asm volatile("s_waitcnt vmcnt(4)" ::: "memory");   // tile kt+1 fully landed
    } else {
      asm volatile("s_waitcnt vmcnt(0)" ::: "memory");
    }
    __builtin_amdgcn_s_barrier();            // buf^1 ready for everyone
  }
#undef STAGE

  // epilogue: scatter to Q/K/V (B,N,T,D); Q pre-scaled by log2e/8
  const int ccol = n0 + wc * 64;
  const int which = ccol >> 10;              // uniform per wave (64-col slice)
  bf16* __restrict__ dst = (which == 0) ? Qb : (which == 1) ? Kb : Vb;
  const float qsc = (which == 0) ? 0.125f * 1.4426950408889634f : 1.0f;
#pragma unroll
  for (int m = 0; m < 8; ++m)
#pragma unroll
    for (int n = 0; n < 4; ++n) {
      int gc = ccol + n*16 + l16;
      float bv = bias[gc];
      int c = gc & (CC-1), head = c >> 6, d = c & 63;
#pragma unroll
      for (int j = 0; j < 4; ++j) {
        int gr = m0 + wr*128 + m*16 + l4*4 + j;
        int b = gr >> 11, t = gr & (TT-1);
        dst[(((size_t)b*NHEAD + head)*TT + t)*DHEAD + d] = f2b((acc[m][n][j] + bv) * qsc);
      }
    }
}

// ---------------- 128x128 bf16 GEMM (m97 structure + XCD swizzle) — proj ----------------
__global__ __launch_bounds__(256)
void k_gemm_proj(const bf16* __restrict__ A, const bf16* __restrict__ Bt,
                 const float* __restrict__ bias, float* __restrict__ outF, int K)
{
  const int tid  = threadIdx.x;
  const int wave = tid >> 6, lane = tid & 63;
  const int l16 = lane & 15, l4 = lane >> 4;
  const int wr = wave >> 1, wc = wave & 1;

  const int gx = gridDim.x;
  const int flat = blockIdx.y * gx + blockIdx.x;
  const int cpx = (gx * gridDim.y) >> 3;
  const int swz = (flat & 7) * cpx + (flat >> 3);
  const int bx = swz % gx, by = swz / gx;
  const int m0 = by * 128, n0 = bx * 128;

  __shared__ __align__(16) bf16 As[128*32];
  __shared__ __align__(16) bf16 Bs[128*32];

  f32x4 acc[4][4];
#pragma unroll
  for (int m = 0; m < 4; ++m)
#pragma unroll
    for (int n = 0; n < 4; ++n) acc[m][n] = 0.f;

  const int sr = tid >> 2;
  const int sc = (tid & 3) * 8;

  for (int k0 = 0; k0 < K; k0 += 32) {
    __syncthreads();
#pragma unroll
    for (int i = 0; i < 2; ++i) {
      gload16(&A [(size_t)(m0 + i*64 + sr) * K + k0 + sc], &As[i*2048 + tid*8]);
      gload16(&Bt[(size_t)(n0 + i*64 + sr) * K + k0 + sc], &Bs[i*2048 + tid*8]);
    }
    __syncthreads();
    bf16x8 af[4], bfr[4];
#pragma unroll
    for (int m = 0; m < 4; ++m)
      af[m] = *reinterpret_cast<const bf16x8*>(&As[(wr*64 + m*16 + l16)*32 + l4*8]);
#pragma unroll
    for (int n = 0; n < 4; ++n)
      bfr[n] = *reinterpret_cast<const bf16x8*>(&Bs[(wc*64 + n*16 + l16)*32 + l4*8]);
#pragma unroll
    for (int m = 0; m < 4; ++m)
#pragma unroll
      for (int n = 0; n < 4; ++n)
        acc[m][n] = __builtin_amdgcn_mfma_f32_16x16x32_bf16(af[m], bfr[n], acc[m][n], 0, 0, 0);
  }

#pragma unroll
  for (int m = 0; m < 4; ++m)
#pragma unroll
    for (int n = 0; n < 4; ++n)
#pragma unroll
      for (int j = 0; j < 4; ++j) {
        int gr = m0 + wr*64 + m*16 + l4*4 + j;
        int gc = n0 + wc*64 + n*16 + l16;
        outF[(size_t)gr * CC + gc] = acc[m][n][j] + bias[gc];
      }
}

// ---------------- flash attention v8 (R9, unchanged) ----------------
__global__ __launch_bounds__(512, 2)
void k_attn(const bf16* __restrict__ Qg, const bf16* __restrict__ Kg,
            const bf16* __restrict__ VTg, bf16* __restrict__ Aout)
{
  const int tid  = threadIdx.x;
  const int wave = tid >> 6, lane = tid & 63;
  const int l16 = lane & 15, l4 = lane >> 4;

  const int flat = blockIdx.x;               // 0..511
  const int xcd = flat & 7, i6 = flat >> 3;
  const int bn = xcd*4 + (i6 >> 4);
  const int q0 = (i6 & 15) * 128;
  const int b = bn >> 4, h = bn & (NHEAD-1);

  __shared__ __align__(16) bf16 Ks[KVB][72];
  __shared__ __align__(16) bf16 Vt[DHEAD][136];
  __shared__ __align__(16) bf16 Pl[8][16][136];

  const size_t hb = (size_t)bn * TT * DHEAD;
  const bf16* __restrict__ Kbase = Kg + hb;
  const bf16* __restrict__ Vbase = VTg + hb;

  bf16x8 qf[2];
#pragma unroll
  for (int kk = 0; kk < 2; ++kk)
    qf[kk] = *reinterpret_cast<const bf16x8*>(
        &Qg[hb + (size_t)(q0 + wave*16 + l16) * DHEAD + kk*32 + l4*8]);

  f32x4 o[4];
#pragma unroll
  for (int n = 0; n < 4; ++n) o[n] = 0.f;
  float mrun = -1e30f, lrun = 0.f;

  const int krow = tid >> 2, kcol = (tid & 3) * 16;
  const int vrow = tid >> 3, vcol = (tid & 7) * 16;

  bf16x8 kreg[2], vreg[2];
#pragma unroll
  for (int i = 0; i < 2; ++i) {
    kreg[i] = *reinterpret_cast<const bf16x8*>(&Kbase[(size_t)krow * DHEAD + kcol + 8*i]);
    vreg[i] = *reinterpret_cast<const bf16x8*>(&Vbase[(size_t)vrow * TT + vcol + 8*i]);
  }
#pragma unroll
  for (int i = 0; i < 2; ++i) {
    *reinterpret_cast<bf16x8*>(&Ks[krow][kcol + 8*i]) = kreg[i];
    *reinterpret_cast<bf16x8*>(&Vt[vrow][vcol + 8*i]) = vreg[i];
  }

  for (int t0 = 0; t0 < TT; t0 += KVB) {
    __syncthreads();
    const bool more = (t0 + KVB < TT);
    if (more) {
#pragma unroll
      for (int i = 0; i < 2; ++i) {
        kreg[i] = *reinterpret_cast<const bf16x8*>(
            &Kbase[(size_t)(t0 + KVB + krow) * DHEAD + kcol + 8*i]);
        vreg[i] = *reinterpret_cast<const bf16x8*>(
            &Vbase[(size_t)vrow * TT + t0 + KVB + vcol + 8*i]);
      }
    }

    f32x4 s[8];
#pragma unroll
    for (int n = 0; n < 8; ++n) s[n] = 0.f;
    __builtin_amdgcn_s_setprio(1);
#pragma unroll
    for (int n = 0; n < 8; ++n) {
      bf16x8 kf0 = *reinterpret_cast<const bf16x8*>(&Ks[n*16 + l16][l4*8]);
      bf16x8 kf1 = *reinterpret_cast<const bf16x8*>(&Ks[n*16 + l16][32 + l4*8]);
      s[n] = __builtin_amdgcn_mfma_f32_16x16x32_bf16(kf0, qf[0], s[n], 0, 0, 0);
      s[n] = __builtin_amdgcn_mfma_f32_16x16x32_bf16(kf1, qf[1], s[n], 0, 0, 0);
    }
    __builtin_amdgcn_s_setprio(0);

    float pm = s[0][0];
#pragma unroll
    for (int n = 0; n < 8; ++n)
#pragma unroll
      for (int j = 0; j < 4; ++j) pm = fmaxf(pm, s[n][j]);
    pm = fmaxf(pm, __shfl_xor(pm, 16, 64));
    pm = fmaxf(pm, __shfl_xor(pm, 32, 64));

    if (!__all(pm <= mrun + 8.f)) {
      float mn = fmaxf(mrun, pm);
      float corr = fast_exp2(mrun - mn);
      mrun = mn;
      lrun *= corr;
      float cj[4];
#pragma unroll
      for (int j = 0; j < 4; ++j)
        cj[j] = __shfl(corr, ((lane >> 4) << 2) + j, 64);
#pragma unroll
      for (int n = 0; n < 4; ++n)
#pragma unroll
        for (int j = 0; j < 4; ++j) o[n][j] *= cj[j];
    }

    float psum = 0.f;
#pragma unroll
    for (int n = 0; n < 8; ++n) {
      bf16x4 pk;
#pragma unroll
      for (int j = 0; j < 4; ++j) {
        float pv = fast_exp2(s[n][j] - mrun);
        psum += pv;
        pk[j] = (__bf16)pv;
      }
      *reinterpret_cast<bf16x4*>(&Pl[wave][l16][n*16 + l4*4]) = pk;
    }
    psum += __shfl_xor(psum, 16, 64);
    psum += __shfl_xor(psum, 32, 64);
    lrun += psum;

    bf16x8 pf[4];
#pragma unroll
    for (int kk = 0; kk < 4; ++kk)
      pf[kk] = *reinterpret_cast<const bf16x8*>(&Pl[wave][l16][kk*32 + l4*8]);
    __builtin_amdgcn_s_setprio(1);
#pragma unroll
    for (int n = 0; n < 4; ++n)
#pragma unroll
      for (int kk = 0; kk < 4; ++kk) {
        bf16x8 vf = *reinterpret_cast<const bf16x8*>(&Vt[n*16 + l16][kk*32 + l4*8]);
        o[n] = __builtin_amdgcn_mfma_f32_16x16x32_bf16(pf[kk], vf, o[n], 0, 0, 0);
      }
    __builtin_amdgcn_s_setprio(0);

    __syncthreads();
    if (more) {
#pragma unroll
      for (int i = 0; i < 2; ++i) {
        *reinterpret_cast<bf16x8*>(&Ks[krow][kcol + 8*i]) = kreg[i];
        *reinterpret_cast<bf16x8*>(&Vt[vrow][vcol + 8*i]) = vreg[i];
      }
    }
  }

  float linv = 1.0f / lrun;
  float lj[4];
#pragma unroll
  for (int j = 0; j < 4; ++j)
    lj[j] = __shfl(linv, ((lane >> 4) << 2) + j, 64);
#pragma unroll
  for (int j = 0; j < 4; ++j) {
    int gt = q0 + wave*16 + l4*4 + j;
#pragma unroll
    for (int n = 0; n < 4; ++n)
      Aout[((size_t)(b*TT + gt))*CC + h*DHEAD + n*16 + l16] = f2b(o[n][j] * lj[j]);
  }
}

extern "C" void kernel_launch(void* const* d_in, const int* in_sizes, int n_in,
                              void* d_out, int out_size, void* d_ws, size_t ws_size,
                              hipStream_t stream)
{
  const float* x     = (const float*)d_in[0];
  const float* Wqkv  = (const float*)d_in[1];
  const float* bqkv  = (const float*)d_in[2];
  const float* Wproj = (const float*)d_in[3];
  const float* bproj = (const float*)d_in[4];
  float* out = (float*)d_out;

  char* p = (char*)d_ws;
  bf16* Xb     = (bf16*)p;  p += (size_t)MM*CC*2;
  bf16* WqkvT  = (bf16*)p;  p += (size_t)3*CC*CC*2;
  bf16* WprojT = (bf16*)p;  p += (size_t)CC*CC*2;
  bf16* Qb     = (bf16*)p;  p += (size_t)MM*CC*2;
  bf16* Kb     = (bf16*)p;  p += (size_t)MM*CC*2;
  bf16* Vb     = (bf16*)p;  p += (size_t)MM*CC*2;
  bf16* Attn   = (bf16*)p;  p += (size_t)MM*CC*2;
  bf16* VTb    = Xb;

  k_prep<<<8192, 256, 0, stream>>>(x, Xb, Wqkv, WqkvT, Wproj, WprojT);
  k_gemm_qkv<<<192, 512, 0, stream>>>(Xb, WqkvT, bqkv, Qb, Kb, Vb);
  k_vtrans<<<dim3(DHEAD/32, TT/32, BB*NHEAD), dim3(32, 8), 0, stream>>>(Vb, VTb);
  k_attn<<<512, 512, 0, stream>>>(Qb, Kb, VTb, Attn);
  k_gemm_proj<<<dim3(CC/128, MM/128), 256, 0, stream>>>(Attn, WprojT, bproj, out, CC);
}

// Round 11
// 134.630 us; speedup vs baseline: 1.3386x; 1.0145x over previous
//
#include <hip/hip_runtime.h>
#include <hip/hip_bf16.h>

#define BB 2
#define TT 2048
#define CC 1024
#define NHEAD 16
#define DHEAD 64
#define MM (BB*TT)
#define KVB 128

using bf16 = __hip_bfloat16;
typedef __bf16 bf16x8 __attribute__((ext_vector_type(8)));
typedef __bf16 bf16x4 __attribute__((ext_vector_type(4)));
typedef float f32x4 __attribute__((ext_vector_type(4)));

static __device__ __forceinline__ bf16 f2b(float f) { return __float2bfloat16(f); }
static __device__ __forceinline__ float fast_exp2(float f) { return __builtin_amdgcn_exp2f(f); }

// async global -> LDS, 16B per lane (dest wave-uniform base; HW adds lane*16B)
static __device__ __forceinline__ void gload16(const bf16* g, bf16* l) {
  __builtin_amdgcn_global_load_lds((__attribute__((address_space(1))) const void*)g,
                                   (__attribute__((address_space(3))) void*)l, 16, 0, 0);
}

// ------------- fused prep: x->bf16 convert + Wqkv^T + Wproj^T -------------
// grid: [0,1024) convert (4 float4/thread), [1024,4096) Wqkv tiles, [4096,5120) Wproj.
__global__ __launch_bounds__(256)
void k_prep(const float* __restrict__ x, bf16* __restrict__ Xb,
            const float* __restrict__ Wqkv, bf16* __restrict__ WqkvT,
            const float* __restrict__ Wproj, bf16* __restrict__ WprojT)
{
  int bid = blockIdx.x;
  const int tid = threadIdx.x;
  if (bid < 1024) {
    int base = bid * 1024 + tid;
#pragma unroll
    for (int k = 0; k < 4; ++k) {
      int i = base + k * 256;
      float4 v = reinterpret_cast<const float4*>(x)[i];
      bf16 o[4] = { f2b(v.x), f2b(v.y), f2b(v.z), f2b(v.w) };
      reinterpret_cast<uint2*>(Xb)[i] = *reinterpret_cast<uint2*>(o);
    }
    return;
  }
  bid -= 1024;
  __shared__ float tile[32][33];
  const float* W; bf16* WT; int R, Cc, bx, by;
  if (bid < 3072) {
    W = Wqkv;  WT = WqkvT;  R = CC; Cc = 3*CC;
    bx = bid % 96; by = bid / 96;
  } else {
    bid -= 3072;
    W = Wproj; WT = WprojT; R = CC; Cc = CC;
    bx = bid % 32; by = bid / 32;
  }
  int c0 = bx * 32, r0 = by * 32;
  int tx = tid & 31, ty = tid >> 5;   // 32 x 8
#pragma unroll
  for (int i = 0; i < 4; ++i)
    tile[ty + 8*i][tx] = W[(size_t)(r0 + ty + 8*i) * Cc + c0 + tx];
  __syncthreads();
#pragma unroll
  for (int i = 0; i < 4; ++i)
    WT[(size_t)(c0 + ty + 8*i) * R + r0 + tx] = f2b(tile[tx][ty + 8*i]);
}

// ------------- per-head V (T x D) -> V^T (D x T), bf16 -------------
__global__ void k_vtrans(const bf16* __restrict__ V, bf16* __restrict__ VT) {
  __shared__ bf16 tile[32][33];
  const int bn = blockIdx.z;
  const int d0 = blockIdx.x * 32, t0 = blockIdx.y * 32;
  const size_t base = (size_t)bn * TT * DHEAD;
  int tx = threadIdx.x, ty = threadIdx.y;   // 32 x 8
#pragma unroll
  for (int i = 0; i < 4; ++i)
    tile[ty + 8*i][tx] = V[base + (size_t)(t0 + ty + 8*i) * DHEAD + d0 + tx];
  __syncthreads();
#pragma unroll
  for (int i = 0; i < 4; ++i)
    VT[base + (size_t)(d0 + ty + 8*i) * TT + t0 + tx] = tile[tx][ty + 8*i];
}

// ============ QKV GEMM: 128x256 tile, BK=32, 3-deep dbuf + counted vmcnt ============
// 384 blocks (2/CU), 8 waves (2Mx4N), per-wave 64x64, 16 MFMA/wave per K-tile.
// LDS 73.7KB = 3 bufs x (A 128x32 | B 256x32). 3 loads/thread per stage; vmcnt(6)
// keeps 2 tiles in flight. 2D XCD chunks (6bx x 8by) keep panels L2-resident.
#define NTK 32
__global__ __launch_bounds__(512, 2)
void k_gemm_qkv(const bf16* __restrict__ Ag, const bf16* __restrict__ Bg,
                const float* __restrict__ bias,
                bf16* __restrict__ Qb, bf16* __restrict__ Kb, bf16* __restrict__ Vb)
{
  const int tid = threadIdx.x;
  const int w = tid >> 6, l = tid & 63;
  const int l16 = l & 15, l4 = l >> 4;
  const int wr = w >> 2, wc = w & 3;          // 2 x 4 wave grid

  // XCD 2D chunking: 384 = 8 XCDs x 48 (6 bx x 8 by)
  const int flat = blockIdx.x;
  const int xcd = flat & 7, local = flat >> 3;       // 0..47
  const int bx = (xcd & 1) * 6 + local % 6;          // 0..11  (N/256)
  const int by = (xcd >> 1) * 8 + local / 6;         // 0..31  (M/128)
  const int m0 = by * 128, n0 = bx * 256;

  __shared__ __align__(16) bf16 sm[36864];    // 3 x 12288 elems = 73.7KB

  f32x4 acc[4][4];
#pragma unroll
  for (int m = 0; m < 4; ++m)
#pragma unroll
    for (int n = 0; n < 4; ++n) acc[m][n] = 0.f;

  // staging: thread covers row tid>>2, swizzled 8-elem slot (source-swizzled)
  const int srow = tid >> 2;
  const int scol = ((tid & 3) ^ ((tid >> 3) & 3)) * 8;

#define STAGE(buf, kt) do {                                                            \
    const int kb = (kt) * 32 + scol;                                                   \
    gload16(&Ag[(size_t)(m0 +       srow) * CC + kb], &sm[(buf)*12288        + w*512]);\
    gload16(&Bg[(size_t)(n0 +       srow) * CC + kb], &sm[(buf)*12288 + 4096 + w*512]);\
    gload16(&Bg[(size_t)(n0 + 128 + srow) * CC + kb], &sm[(buf)*12288 + 8192 + w*512]);\
  } while (0)

  STAGE(0, 0);
  STAGE(1, 1);
  STAGE(2, 2);
  asm volatile("s_waitcnt vmcnt(6)" ::: "memory");   // tile0's 3 loads done
  __builtin_amdgcn_s_barrier();

  const int slotA = (l4 ^ ((l16 >> 1) & 3)) * 8;     // swizzled 8-elem slot offset
  const int aoff = wr * 2048 + l16 * 32 + slotA;                 // + m*512
  const int boff = 4096 + wc * 2048 + l16 * 32 + slotA;          // + n*512

  int rb = 0;
  for (int kt = 0; kt < NTK; ++kt) {
    const int base = rb * 12288;

    bf16x8 af[4], bfr[4];
#pragma unroll
    for (int m = 0; m < 4; ++m)
      af[m] = *reinterpret_cast<const bf16x8*>(&sm[base + aoff + m*512]);
#pragma unroll
    for (int n = 0; n < 4; ++n)
      bfr[n] = *reinterpret_cast<const bf16x8*>(&sm[base + boff + n*512]);
    __builtin_amdgcn_s_setprio(1);
#pragma unroll
    for (int m = 0; m < 4; ++m)
#pragma unroll
      for (int n = 0; n < 4; ++n)
        acc[m][n] = __builtin_amdgcn_mfma_f32_16x16x32_bf16(af[m], bfr[n], acc[m][n], 0, 0, 0);
    __builtin_amdgcn_s_setprio(0);

    __builtin_amdgcn_s_barrier();            // all waves done reading buf rb
    if (kt + 3 < NTK) {
      STAGE(rb, kt + 3);                     // refill rb with tile kt+3 (9 in flight)
      asm volatile("s_waitcnt vmcnt(6)" ::: "memory");   // tile kt+1 fully landed
    } else if (kt + 2 < NTK) {
      asm volatile("s_waitcnt vmcnt(3)" ::: "memory");
    } else if (kt + 1 < NTK) {
      asm volatile("s_waitcnt vmcnt(0)" ::: "memory");
    }
    __builtin_amdgcn_s_barrier();            // next buf ready for everyone
    rb = (rb + 1 == 3) ? 0 : rb + 1;
  }
#undef STAGE

  // epilogue: scatter to Q/K/V (B,N,T,D); Q pre-scaled by log2e/8
  const int ccol = n0 + wc * 64;
  const int which = ccol >> 10;              // uniform per wave
  bf16* __restrict__ dst = (which == 0) ? Qb : (which == 1) ? Kb : Vb;
  const float qsc = (which == 0) ? 0.125f * 1.4426950408889634f : 1.0f;
#pragma unroll
  for (int m = 0; m < 4; ++m)
#pragma unroll
    for (int n = 0; n < 4; ++n) {
      int gc = ccol + n*16 + l16;
      float bv = bias[gc];
      int c = gc & (CC-1), head = c >> 6, d = c & 63;
#pragma unroll
      for (int j = 0; j < 4; ++j) {
        int gr = m0 + wr*64 + m*16 + l4*4 + j;
        int b = gr >> 11, t = gr & (TT-1);
        dst[(((size_t)b*NHEAD + head)*TT + t)*DHEAD + d] = f2b((acc[m][n][j] + bv) * qsc);
      }
    }
}

// ---------------- 128x128 bf16 GEMM (m97 structure + XCD swizzle) — proj ----------------
__global__ __launch_bounds__(256)
void k_gemm_proj(const bf16* __restrict__ A, const bf16* __restrict__ Bt,
                 const float* __restrict__ bias, float* __restrict__ outF, int K)
{
  const int tid  = threadIdx.x;
  const int wave = tid >> 6, lane = tid & 63;
  const int l16 = lane & 15, l4 = lane >> 4;
  const int wr = wave >> 1, wc = wave & 1;

  const int gx = gridDim.x;
  const int flat = blockIdx.y * gx + blockIdx.x;
  const int cpx = (gx * gridDim.y) >> 3;
  const int swz = (flat & 7) * cpx + (flat >> 3);
  const int bx = swz % gx, by = swz / gx;
  const int m0 = by * 128, n0 = bx * 128;

  __shared__ __align__(16) bf16 As[128*32];
  __shared__ __align__(16) bf16 Bs[128*32];

  f32x4 acc[4][4];
#pragma unroll
  for (int m = 0; m < 4; ++m)
#pragma unroll
    for (int n = 0; n < 4; ++n) acc[m][n] = 0.f;

  const int sr = tid >> 2;
  const int sc = (tid & 3) * 8;

  for (int k0 = 0; k0 < K; k0 += 32) {
    __syncthreads();
#pragma unroll
    for (int i = 0; i < 2; ++i) {
      gload16(&A [(size_t)(m0 + i*64 + sr) * K + k0 + sc], &As[i*2048 + tid*8]);
      gload16(&Bt[(size_t)(n0 + i*64 + sr) * K + k0 + sc], &Bs[i*2048 + tid*8]);
    }
    __syncthreads();
    bf16x8 af[4], bfr[4];
#pragma unroll
    for (int m = 0; m < 4; ++m)
      af[m] = *reinterpret_cast<const bf16x8*>(&As[(wr*64 + m*16 + l16)*32 + l4*8]);
#pragma unroll
    for (int n = 0; n < 4; ++n)
      bfr[n] = *reinterpret_cast<const bf16x8*>(&Bs[(wc*64 + n*16 + l16)*32 + l4*8]);
#pragma unroll
    for (int m = 0; m < 4; ++m)
#pragma unroll
      for (int n = 0; n < 4; ++n)
        acc[m][n] = __builtin_amdgcn_mfma_f32_16x16x32_bf16(af[m], bfr[n], acc[m][n], 0, 0, 0);
  }

#pragma unroll
  for (int m = 0; m < 4; ++m)
#pragma unroll
    for (int n = 0; n < 4; ++n)
#pragma unroll
      for (int j = 0; j < 4; ++j) {
        int gr = m0 + wr*64 + m*16 + l4*4 + j;
        int gc = n0 + wc*64 + n*16 + l16;
        outF[(size_t)gr * CC + gc] = acc[m][n][j] + bias[gc];
      }
}

// ---------------- flash attention v8 (R9, unchanged) ----------------
__global__ __launch_bounds__(512, 2)
void k_attn(const bf16* __restrict__ Qg, const bf16* __restrict__ Kg,
            const bf16* __restrict__ VTg, bf16* __restrict__ Aout)
{
  const int tid  = threadIdx.x;
  const int wave = tid >> 6, lane = tid & 63;
  const int l16 = lane & 15, l4 = lane >> 4;

  const int flat = blockIdx.x;               // 0..511
  const int xcd = flat & 7, i6 = flat >> 3;
  const int bn = xcd*4 + (i6 >> 4);
  const int q0 = (i6 & 15) * 128;
  const int b = bn >> 4, h = bn & (NHEAD-1);

  __shared__ __align__(16) bf16 Ks[KVB][72];
  __shared__ __align__(16) bf16 Vt[DHEAD][136];
  __shared__ __align__(16) bf16 Pl[8][16][136];

  const size_t hb = (size_t)bn * TT * DHEAD;
  const bf16* __restrict__ Kbase = Kg + hb;
  const bf16* __restrict__ Vbase = VTg + hb;

  bf16x8 qf[2];
#pragma unroll
  for (int kk = 0; kk < 2; ++kk)
    qf[kk] = *reinterpret_cast<const bf16x8*>(
        &Qg[hb + (size_t)(q0 + wave*16 + l16) * DHEAD + kk*32 + l4*8]);

  f32x4 o[4];
#pragma unroll
  for (int n = 0; n < 4; ++n) o[n] = 0.f;
  float mrun = -1e30f, lrun = 0.f;

  const int krow = tid >> 2, kcol = (tid & 3) * 16;
  const int vrow = tid >> 3, vcol = (tid & 7) * 16;

  bf16x8 kreg[2], vreg[2];
#pragma unroll
  for (int i = 0; i < 2; ++i) {
    kreg[i] = *reinterpret_cast<const bf16x8*>(&Kbase[(size_t)krow * DHEAD + kcol + 8*i]);
    vreg[i] = *reinterpret_cast<const bf16x8*>(&Vbase[(size_t)vrow * TT + vcol + 8*i]);
  }
#pragma unroll
  for (int i = 0; i < 2; ++i) {
    *reinterpret_cast<bf16x8*>(&Ks[krow][kcol + 8*i]) = kreg[i];
    *reinterpret_cast<bf16x8*>(&Vt[vrow][vcol + 8*i]) = vreg[i];
  }

  for (int t0 = 0; t0 < TT; t0 += KVB) {
    __syncthreads();
    const bool more = (t0 + KVB < TT);
    if (more) {
#pragma unroll
      for (int i = 0; i < 2; ++i) {
        kreg[i] = *reinterpret_cast<const bf16x8*>(
            &Kbase[(size_t)(t0 + KVB + krow) * DHEAD + kcol + 8*i]);
        vreg[i] = *reinterpret_cast<const bf16x8*>(
            &Vbase[(size_t)vrow * TT + t0 + KVB + vcol + 8*i]);
      }
    }

    f32x4 s[8];
#pragma unroll
    for (int n = 0; n < 8; ++n) s[n] = 0.f;
    __builtin_amdgcn_s_setprio(1);
#pragma unroll
    for (int n = 0; n < 8; ++n) {
      bf16x8 kf0 = *reinterpret_cast<const bf16x8*>(&Ks[n*16 + l16][l4*8]);
      bf16x8 kf1 = *reinterpret_cast<const bf16x8*>(&Ks[n*16 + l16][32 + l4*8]);
      s[n] = __builtin_amdgcn_mfma_f32_16x16x32_bf16(kf0, qf[0], s[n], 0, 0, 0);
      s[n] = __builtin_amdgcn_mfma_f32_16x16x32_bf16(kf1, qf[1], s[n], 0, 0, 0);
    }
    __builtin_amdgcn_s_setprio(0);

    float pm = s[0][0];
#pragma unroll
    for (int n = 0; n < 8; ++n)
#pragma unroll
      for (int j = 0; j < 4; ++j) pm = fmaxf(pm, s[n][j]);
    pm = fmaxf(pm, __shfl_xor(pm, 16, 64));
    pm = fmaxf(pm, __shfl_xor(pm, 32, 64));

    if (!__all(pm <= mrun + 8.f)) {
      float mn = fmaxf(mrun, pm);
      float corr = fast_exp2(mrun - mn);
      mrun = mn;
      lrun *= corr;
      float cj[4];
#pragma unroll
      for (int j = 0; j < 4; ++j)
        cj[j] = __shfl(corr, ((lane >> 4) << 2) + j, 64);
#pragma unroll
      for (int n = 0; n < 4; ++n)
#pragma unroll
        for (int j = 0; j < 4; ++j) o[n][j] *= cj[j];
    }

    float psum = 0.f;
#pragma unroll
    for (int n = 0; n < 8; ++n) {
      bf16x4 pk;
#pragma unroll
      for (int j = 0; j < 4; ++j) {
        float pv = fast_exp2(s[n][j] - mrun);
        psum += pv;
        pk[j] = (__bf16)pv;
      }
      *reinterpret_cast<bf16x4*>(&Pl[wave][l16][n*16 + l4*4]) = pk;
    }
    psum += __shfl_xor(psum, 16, 64);
    psum += __shfl_xor(psum, 32, 64);
    lrun += psum;

    bf16x8 pf[4];
#pragma unroll
    for (int kk = 0; kk < 4; ++kk)
      pf[kk] = *reinterpret_cast<const bf16x8*>(&Pl[wave][l16][kk*32 + l4*8]);
    __builtin_amdgcn_s_setprio(1);
#pragma unroll
    for (int n = 0; n < 4; ++n)
#pragma unroll
      for (int kk = 0; kk < 4; ++kk) {
        bf16x8 vf = *reinterpret_cast<const bf16x8*>(&Vt[n*16 + l16][kk*32 + l4*8]);
        o[n] = __builtin_amdgcn_mfma_f32_16x16x32_bf16(pf[kk], vf, o[n], 0, 0, 0);
      }
    __builtin_amdgcn_s_setprio(0);

    __syncthreads();
    if (more) {
#pragma unroll
      for (int i = 0; i < 2; ++i) {
        *reinterpret_cast<bf16x8*>(&Ks[krow][kcol + 8*i]) = kreg[i];
        *reinterpret_cast<bf16x8*>(&Vt[vrow][vcol + 8*i]) = vreg[i];
      }
    }
  }

  float linv = 1.0f / lrun;
  float lj[4];
#pragma unroll
  for (int j = 0; j < 4; ++j)
    lj[j] = __shfl(linv, ((lane >> 4) << 2) + j, 64);
#pragma unroll
  for (int j = 0; j < 4; ++j) {
    int gt = q0 + wave*16 + l4*4 + j;
#pragma unroll
    for (int n = 0; n < 4; ++n)
      Aout[((size_t)(b*TT + gt))*CC + h*DHEAD + n*16 + l16] = f2b(o[n][j] * lj[j]);
  }
}

extern "C" void kernel_launch(void* const* d_in, const int* in_sizes, int n_in,
                              void* d_out, int out_size, void* d_ws, size_t ws_size,
                              hipStream_t stream)
{
  const float* x     = (const float*)d_in[0];
  const float* Wqkv  = (const float*)d_in[1];
  const float* bqkv  = (const float*)d_in[2];
  const float* Wproj = (const float*)d_in[3];
  const float* bproj = (const float*)d_in[4];
  float* out = (float*)d_out;

  char* p = (char*)d_ws;
  bf16* Xb     = (bf16*)p;  p += (size_t)MM*CC*2;
  bf16* WqkvT  = (bf16*)p;  p += (size_t)3*CC*CC*2;
  bf16* WprojT = (bf16*)p;  p += (size_t)CC*CC*2;
  bf16* Qb     = (bf16*)p;  p += (size_t)MM*CC*2;
  bf16* Kb     = (bf16*)p;  p += (size_t)MM*CC*2;
  bf16* Vb     = (bf16*)p;  p += (size_t)MM*CC*2;
  bf16* Attn   = (bf16*)p;  p += (size_t)MM*CC*2;
  bf16* VTb    = Xb;

  k_prep<<<5120, 256, 0, stream>>>(x, Xb, Wqkv, WqkvT, Wproj, WprojT);
  k_gemm_qkv<<<384, 512, 0, stream>>>(Xb, WqkvT, bqkv, Qb, Kb, Vb);
  k_vtrans<<<dim3(DHEAD/32, TT/32, BB*NHEAD), dim3(32, 8), 0, stream>>>(Vb, VTb);
  k_attn<<<512, 512, 0, stream>>>(Qb, Kb, VTb, Attn);
  k_gemm_proj<<<dim3(CC/128, MM/128), 256, 0, stream>>>(Attn, WprojT, bproj, out, CC);
}